// Round 2
// baseline (1024.959 us; speedup 1.0000x reference)
//
#include <hip/hip_runtime.h>
#include <cstdint>
#include <cstddef>

#define NE 8
#define DMODEL 768
#define MLPDIM 3072
#define NDET 16384
#define NCLS 4096
#define NTOK 20480
#define ROWS_PER_E 5120   /* 16*256 (det) + 8*128 (cls) */
#define TOT_ROWS 40960

typedef float f32x4 __attribute__((ext_vector_type(4)));
typedef __bf16 bf16x8 __attribute__((ext_vector_type(8)));

__device__ __forceinline__ unsigned short f2bf(float f) {
    unsigned u = __float_as_uint(f);
    u += 0x7FFFu + ((u >> 16) & 1u);   // RNE
    return (unsigned short)(u >> 16);
}
__device__ __forceinline__ float bf2f(unsigned v) {
    return __uint_as_float(v << 16);
}
__device__ __forceinline__ float gelu_f(float x) {
    // jax.nn.gelu approximate=True (tanh form)
    float u = 0.7978845608028654f * (x + 0.044715f * x * x * x);
    float a = fabsf(u);
    float t = __expf(-2.0f * a);
    float th = (1.0f - t) / (1.0f + t);
    th = (u >= 0.0f) ? th : -th;
    return 0.5f * x * (1.0f + th);
}

// async global->LDS, 16B per lane; dst is wave-uniform base, HW adds lane*16
__device__ __forceinline__ void gload16(const void* g, void* l) {
    __builtin_amdgcn_global_load_lds(
        (const __attribute__((address_space(1))) unsigned int*)g,
        (__attribute__((address_space(3))) unsigned int*)l, 16, 0, 0);
}

// ---------------- router (fp32) + x->bf16 conversion fused ----------------
__global__ void k_router(const float* __restrict__ xd, const float* __restrict__ xc,
                         const float* __restrict__ wrd, const float* __restrict__ wrc,
                         ushort* __restrict__ xbf,
                         int* __restrict__ e1, int* __restrict__ e2,
                         float* __restrict__ g1, float* __restrict__ g2) {
    int wave = threadIdx.x >> 6, lane = threadIdx.x & 63;
    int t = blockIdx.x * 4 + wave;
    if (t >= NTOK) return;
    const float* xrow;
    const float* w;
    if (t < NDET) { xrow = xd + (size_t)t * DMODEL; w = wrd; }
    else          { xrow = xc + (size_t)(t - NDET) * DMODEL; w = wrc; }
    ushort* xbrow = xbf + (size_t)t * DMODEL;
    float acc[8];
    #pragma unroll
    for (int e = 0; e < 8; e++) acc[e] = 0.0f;
    #pragma unroll
    for (int kk = 0; kk < DMODEL / 64; kk++) {
        int k = kk * 64 + lane;
        float xv = xrow[k];
        xbrow[k] = f2bf(xv);              // fused bf16 conversion
        const float* wr = w + k * 8;
        #pragma unroll
        for (int e = 0; e < 8; e++) acc[e] += xv * wr[e];
    }
    #pragma unroll
    for (int e = 0; e < 8; e++) {
        #pragma unroll
        for (int off = 32; off > 0; off >>= 1) acc[e] += __shfl_xor(acc[e], off);
    }
    // top-2 with lower-index tie-break (lax.top_k)
    int i1 = 0; float v1 = acc[0];
    #pragma unroll
    for (int e = 1; e < 8; e++) if (acc[e] > v1) { v1 = acc[e]; i1 = e; }
    int i2 = -1; float v2 = -1e30f;
    #pragma unroll
    for (int e = 0; e < 8; e++) if (e != i1 && acc[e] > v2) { v2 = acc[e]; i2 = e; }
    float Z = 0.0f;
    #pragma unroll
    for (int e = 0; e < 8; e++) Z += __expf(acc[e] - v1);
    if (lane == 0) {
        e1[t] = i1; e2[t] = i2;
        g1[t] = 1.0f / Z;
        g2[t] = __expf(v2 - v1) / Z;
    }
}

// ---------------- w [E][K][N] fp32 -> [E][N][K] bf16 ----------------
__global__ void k_transpose_bf(const float* __restrict__ in, ushort* __restrict__ out,
                               int K, int N) {
    __shared__ float tile[32][33];
    int e = blockIdx.z;
    const float* A = in + (size_t)e * K * N;
    ushort* B = out + (size_t)e * N * K;
    int n0 = blockIdx.x * 32, k0 = blockIdx.y * 32;
    for (int i = threadIdx.y; i < 32; i += 8)
        tile[i][threadIdx.x] = A[(size_t)(k0 + i) * N + n0 + threadIdx.x];
    __syncthreads();
    for (int i = threadIdx.y; i < 32; i += 8)
        B[(size_t)(n0 + i) * K + k0 + threadIdx.x] = f2bf(tile[threadIdx.x][i]);
}

// ---------------- capacity scan: one wave per group, k-major order ----------------
__global__ void k_scan(const int* __restrict__ e1, const int* __restrict__ e2,
                       int* __restrict__ slot_map, int* __restrict__ r1, int* __restrict__ r2) {
    int g = blockIdx.x;          // 0..15 det, 16..23 cls
    int lane = threadIdx.x;      // 64 threads
    int S, C, base;
    if (g < 16) { S = 1024; C = 256; base = g * 1024; }
    else        { S = 512;  C = 128; base = NDET + (g - 16) * 512; }
    int cnt[8];
    #pragma unroll
    for (int e = 0; e < 8; e++) cnt[e] = 0;
    unsigned long long lower = (lane == 0) ? 0ULL : ((~0ULL) >> (64 - lane));
    int nch = (2 * S) >> 6;
    for (int ch = 0; ch < nch; ch++) {
        int n = ch * 64 + lane;
        int k = (n >= S) ? 1 : 0;
        int s = n - k * S;
        int tok = base + s;
        int e = k ? e2[tok] : e1[tok];
        int pos = 0;
        #pragma unroll
        for (int ee = 0; ee < 8; ee++) {
            unsigned long long m = __ballot(e == ee);
            if (e == ee) pos = cnt[ee] + __popcll(m & lower);
            cnt[ee] += __popcll(m);
        }
        int r = -1;
        if (pos < C) {
            int local = (g < 16) ? (g * 256 + pos) : (4096 + (g - 16) * 128 + pos);
            r = e * ROWS_PER_E + local;
            slot_map[r] = tok;
        }
        if (k == 0) r1[tok] = r; else r2[tok] = r;
    }
}

// ---------------- m97-structure GEMM: C = op(A @ Bt + bias) ----------------
// 128x128 tile, BK=32, 4 waves, global_load_lds(16B) staging, linear LDS.
// A rows gathered via smap when smap!=nullptr (tok<0 -> row 0, output unread).
// Expert id = row-block / rpe selects B panel + bias.
template<int KTOT, int NTOT, bool GELU>
__global__ __launch_bounds__(256) void k_gemm(
    const ushort* __restrict__ Asrc, const int* __restrict__ smap,
    const ushort* __restrict__ BtBase, const float* __restrict__ biasBase,
    ushort* __restrict__ Cout, int rpe, int nbn) {
    constexpr int KSTEPS = KTOT / 32;
    __shared__ __align__(1024) ushort As[128 * 32];
    __shared__ __align__(1024) ushort Bs[128 * 32];

    // bijective XCD-chunked swizzle (gridDim.x % 8 == 0), n-fastest walk
    const int nwg = gridDim.x;
    const int q = nwg >> 3;
    const int id2 = (blockIdx.x & 7) * q + (blockIdx.x >> 3);
    const int mb = id2 / nbn, nb = id2 - mb * nbn;
    const int e = mb / rpe;
    const int m0 = mb * 128, n0 = nb * 128;
    const ushort* Bt = BtBase + (size_t)e * KTOT * NTOT;
    const float* bias = biasBase + (size_t)e * NTOT;

    const int t = threadIdx.x, lane = t & 63, wave = t >> 6;

    // staging: wave stages As rows [wave*32, wave*32+32) and same for Bs,
    // as two 1KB global_load_lds each (16 rows x 64B). lane -> row base + (l>>2),
    // byte (l&3)*16 within the row's 64B K-chunk.
    const int sr0 = wave * 32 + (lane >> 2);
    const int sr1 = sr0 + 16;
    const int cb = (lane & 3) * 16;
    const char* a0;
    const char* a1;
    if (smap) {
        int t0 = smap[m0 + sr0], t1 = smap[m0 + sr1];
        a0 = (const char*)(Asrc + (size_t)(t0 < 0 ? 0 : t0) * KTOT) + cb;
        a1 = (const char*)(Asrc + (size_t)(t1 < 0 ? 0 : t1) * KTOT) + cb;
    } else {
        a0 = (const char*)(Asrc + (size_t)(m0 + sr0) * KTOT) + cb;
        a1 = (const char*)(Asrc + (size_t)(m0 + sr1) * KTOT) + cb;
    }
    const char* b0 = (const char*)(Bt + (size_t)(n0 + sr0) * KTOT) + cb;
    const char* b1 = (const char*)(Bt + (size_t)(n0 + sr1) * KTOT) + cb;
    ushort* dA0 = As + (wave * 32) * 32;
    ushort* dA1 = As + (wave * 32 + 16) * 32;
    ushort* dB0 = Bs + (wave * 32) * 32;
    ushort* dB1 = Bs + (wave * 32 + 16) * 32;

    auto ISSUE = [&](int ks) {
        size_t off = (size_t)ks * 64;
        gload16(a0 + off, dA0);
        gload16(a1 + off, dA1);
        gload16(b0 + off, dB0);
        gload16(b1 + off, dB1);
    };

    const int wr = wave >> 1, wc = wave & 1;
    const int koff = (lane >> 4) * 8;
    const int arow = wr * 64 + (lane & 15);
    const int brow = wc * 64 + (lane & 15);

    f32x4 acc[4][4] = {};
    ISSUE(0);
    for (int ks = 0; ks < KSTEPS; ks++) {
        __syncthreads();               // drains vmcnt: tile ks visible in LDS
        bf16x8 af[4], bfr[4];
        #pragma unroll
        for (int mt = 0; mt < 4; mt++)
            af[mt] = *(const bf16x8*)(As + (arow + mt * 16) * 32 + koff);
        #pragma unroll
        for (int nt = 0; nt < 4; nt++)
            bfr[nt] = *(const bf16x8*)(Bs + (brow + nt * 16) * 32 + koff);
        __syncthreads();               // drains lgkm: all waves done reading LDS
        if (ks + 1 < KSTEPS) ISSUE(ks + 1);   // async loads overlap MFMA
        #pragma unroll
        for (int mt = 0; mt < 4; mt++) {
            #pragma unroll
            for (int nt = 0; nt < 4; nt++)
                acc[mt][nt] = __builtin_amdgcn_mfma_f32_16x16x32_bf16(af[mt], bfr[nt], acc[mt][nt], 0, 0, 0);
        }
    }

    // epilogue: C/D layout col=lane&15, row=(lane>>4)*4+j  (verified round 1)
    const int crow_base = m0 + wr * 64;
    const int ccol_base = n0 + wc * 64;
    #pragma unroll
    for (int nt = 0; nt < 4; nt++) {
        int col = ccol_base + nt * 16 + (lane & 15);
        float bv = bias[col];
        #pragma unroll
        for (int mt = 0; mt < 4; mt++) {
            #pragma unroll
            for (int j = 0; j < 4; j++) {
                int row = crow_base + mt * 16 + (lane >> 4) * 4 + j;
                float v = acc[mt][nt][j] + bv;
                if (GELU) v = gelu_f(v);
                Cout[(size_t)row * NTOT + col] = f2bf(v);
            }
        }
    }
}

// ---------------- combine: out[token] = g1*y[r1] + g2*y[r2] ----------------
__global__ void k_combine(const ushort* __restrict__ y,
                          const int* __restrict__ r1, const int* __restrict__ r2,
                          const float* __restrict__ g1, const float* __restrict__ g2,
                          float* __restrict__ out) {
    int t = blockIdx.x;
    int d = threadIdx.x;          // 192 threads, 4 floats each
    int a = r1[t], b = r2[t];
    float wa = g1[t], wb = g2[t];
    size_t opos;
    if (t < NDET) { int bb = t >> 10, s = t & 1023; opos = ((size_t)bb * 1280 + s) * 768; }
    else { int tt = t - NDET; int bb = tt >> 8, s = tt & 255; opos = ((size_t)bb * 1280 + 1024 + s) * 768; }
    int di = d * 4;
    float4 o = make_float4(0.f, 0.f, 0.f, 0.f);
    if (a >= 0) {
        uint2 v = *(const uint2*)(y + (size_t)a * 768 + di);
        o.x += wa * bf2f(v.x & 0xffffu); o.y += wa * bf2f(v.x >> 16);
        o.z += wa * bf2f(v.y & 0xffffu); o.w += wa * bf2f(v.y >> 16);
    }
    if (b >= 0) {
        uint2 v = *(const uint2*)(y + (size_t)b * 768 + di);
        o.x += wb * bf2f(v.x & 0xffffu); o.y += wb * bf2f(v.x >> 16);
        o.z += wb * bf2f(v.y & 0xffffu); o.w += wb * bf2f(v.y >> 16);
    }
    *(float4*)(out + opos + di) = o;
}

extern "C" void kernel_launch(void* const* d_in, const int* in_sizes, int n_in,
                              void* d_out, int out_size, void* d_ws, size_t ws_size,
                              hipStream_t stream) {
    const float* xd  = (const float*)d_in[0];
    const float* xc  = (const float*)d_in[1];
    const float* wrd = (const float*)d_in[2];
    const float* wrc = (const float*)d_in[3];
    const float* w1  = (const float*)d_in[4];
    const float* b1  = (const float*)d_in[5];
    const float* w2  = (const float*)d_in[6];
    const float* b2  = (const float*)d_in[7];
    float* out = (float*)d_out;

    size_t off = 0;
    char* base = (char*)d_ws;
    auto alloc = [&](size_t bytes) -> char* {
        char* r = base + off;
        off += (bytes + 255) & ~(size_t)255;
        return r;
    };
    ushort* xbf = (ushort*)alloc((size_t)NTOK * DMODEL * 2);
    ushort* w1t = (ushort*)alloc((size_t)NE * MLPDIM * DMODEL * 2);
    ushort* w2t = (ushort*)alloc((size_t)NE * DMODEL * MLPDIM * 2);
    ushort* y   = (ushort*)alloc((size_t)TOT_ROWS * DMODEL * 2);
    int*   slot_map = (int*)alloc((size_t)TOT_ROWS * 4);
    int*   e1 = (int*)alloc((size_t)NTOK * 4);
    int*   e2 = (int*)alloc((size_t)NTOK * 4);
    float* g1 = (float*)alloc((size_t)NTOK * 4);
    float* g2 = (float*)alloc((size_t)NTOK * 4);
    int*   r1 = (int*)alloc((size_t)NTOK * 4);
    int*   r2 = (int*)alloc((size_t)NTOK * 4);

    const size_t h_full_bytes  = (size_t)TOT_ROWS * MLPDIM * 2;    // 252 MB
    const size_t h_local_bytes = (size_t)ROWS_PER_E * MLPDIM * 2;  // 31.5 MB
    bool batched = (ws_size - off) >= h_full_bytes;
    ushort* h = (ushort*)alloc(batched ? h_full_bytes : h_local_bytes);
    if (off > ws_size) return;   // ws too small even for fallback

    hipMemsetAsync(slot_map, 0xFF, (size_t)TOT_ROWS * 4, stream);   // -1 = empty slot

    k_router<<<NTOK / 4, 256, 0, stream>>>(xd, xc, wrd, wrc, xbf, e1, e2, g1, g2);
    k_transpose_bf<<<dim3(MLPDIM / 32, DMODEL / 32, NE), dim3(32, 8), 0, stream>>>(w1, w1t, DMODEL, MLPDIM);
    k_transpose_bf<<<dim3(DMODEL / 32, MLPDIM / 32, NE), dim3(32, 8), 0, stream>>>(w2, w2t, MLPDIM, DMODEL);
    k_scan<<<24, 64, 0, stream>>>(e1, e2, slot_map, r1, r2);

    if (batched) {
        k_gemm<DMODEL, MLPDIM, true><<<(TOT_ROWS / 128) * (MLPDIM / 128), 256, 0, stream>>>(
            xbf, slot_map, w1t, b1, h, ROWS_PER_E / 128, MLPDIM / 128);
        k_gemm<MLPDIM, DMODEL, false><<<(TOT_ROWS / 128) * (DMODEL / 128), 256, 0, stream>>>(
            h, nullptr, w2t, b2, y, ROWS_PER_E / 128, DMODEL / 128);
    } else {
        for (int e = 0; e < NE; e++) {
            k_gemm<DMODEL, MLPDIM, true><<<(ROWS_PER_E / 128) * (MLPDIM / 128), 256, 0, stream>>>(
                xbf, slot_map + (size_t)e * ROWS_PER_E,
                w1t + (size_t)e * MLPDIM * DMODEL, b1 + (size_t)e * MLPDIM,
                h, 1 << 28, MLPDIM / 128);
            k_gemm<MLPDIM, DMODEL, false><<<(ROWS_PER_E / 128) * (DMODEL / 128), 256, 0, stream>>>(
                h, nullptr,
                w2t + (size_t)e * DMODEL * MLPDIM, b2 + (size_t)e * DMODEL,
                y + (size_t)e * ROWS_PER_E * DMODEL, 1 << 28, DMODEL / 128);
        }
    }

    k_combine<<<NTOK, 192, 0, stream>>>(y, r1, r2, g1, g2, out);
}